// Round 7
// baseline (470.567 us; speedup 1.0000x reference)
//
#include <hip/hip_runtime.h>
#include <hip/hip_bf16.h>

typedef short short8 __attribute__((ext_vector_type(8)));
typedef float float4v __attribute__((ext_vector_type(4)));

#define B_   2
#define L_   1024
#define DIN  512
#define DM   1024
#define DS   16
#define DD   64
#define KER_ 4
#define NROW (B_*L_)     // 2048
#define NBLK 256
#define NTHR 512

// scan geometry (identical to round-6): block = (b, 8 d-lanes); 32x32
#define SD   8
#define SC   32
#define SLC  32
#define SDP  9

__device__ __forceinline__ float silu_f(float v){ return v / (1.f + expf(-v)); }

// packed f32x2 -> bf16x2 RNE (v_cvt_pk_bf16_f32)
__device__ __forceinline__ short2 f2bf2(float a, float b) {
  __hip_bfloat162 h = __float22bfloat162_rn(float2{a, b});
  union { __hip_bfloat162 h; short2 s; } u; u.h = h; return u.s;
}
__device__ __forceinline__ short f2bf1(float a) {
  __hip_bfloat16 h = __float2bfloat16(a);
  union { __hip_bfloat16 h; short s; } u; u.h = h; return u.s;
}
__device__ __forceinline__ short8 pack8(const float4& x0, const float4& x1) {
  short2 s0 = f2bf2(x0.x, x0.y), s1 = f2bf2(x0.z, x0.w);
  short2 s2 = f2bf2(x1.x, x1.y), s3 = f2bf2(x1.z, x1.w);
  return short8{ s0.x, s0.y, s1.x, s1.y, s2.x, s2.y, s3.x, s3.y };
}

// LDS reused across phases (phases separated by barriers)
union SMem {
  struct { short As[128 * 40]; short Bs[128 * 40]; } g1;                    // 20.5 KB
  struct { short xs[16 * 40]; short wsb[96 * 40]; short t1s[16 * 72]; } pj; // 11 KB
  struct { float Pl[SC][DS][SDP]; float Hl[SC][DS][SDP]; } sc;              // 36.9 KB
  struct { short As[64 * 40]; short Bs[64 * 40]; } g2;                      // 10.2 KB
};

// device-scope arrive-and-spin grid barrier. All NBLK blocks are co-resident
// (256 blocks, 8 waves + 37 KB LDS each, <= 1/4 of a CU) so spinning is safe.
__device__ __forceinline__ void grid_barrier(unsigned* cnt, unsigned nblk) {
  __syncthreads();
  if (threadIdx.x == 0) {
    __threadfence();   // release: flush my block's writes to device scope
    __hip_atomic_fetch_add(cnt, 1u, __ATOMIC_ACQ_REL, __HIP_MEMORY_SCOPE_AGENT);
    while (__hip_atomic_load(cnt, __ATOMIC_ACQUIRE, __HIP_MEMORY_SCOPE_AGENT) < nblk)
      __builtin_amdgcn_s_sleep(1);
  }
  __syncthreads();
  __threadfence();     // acquire: invalidate stale cached lines before reads
}

__global__ __launch_bounds__(NTHR)
void mega_k(const float* __restrict__ seq, const float* __restrict__ Win,
            const float* __restrict__ Wout, const float* __restrict__ WB,
            const float* __restrict__ WC, const float* __restrict__ WD1,
            const float* __restrict__ WD2, const float* __restrict__ cw,
            const float* __restrict__ cb, const float* __restrict__ Aa,
            const float* __restrict__ Dv, float* __restrict__ out,
            float* __restrict__ ab, float* __restrict__ dlt,
            float* __restrict__ pall, float* __restrict__ sout,
            unsigned* __restrict__ bar) {
  __shared__ SMem sm;
  const int blk  = blockIdx.x;
  const int tid  = threadIdx.x;
  const int lane = tid & 63;
  const int wave = tid >> 6;
  const int r16  = lane & 15;
  const int quad = lane >> 4;

  // ================= Phase 1: ab[2048,2048] = seq . Win^T =================
  {
    const int m0 = (blk >> 4) * 128;
    const int n0 = (blk & 15) * 128;
    const int wm = wave & 1, wn = wave >> 1;   // 2 x 4 waves, tile 64x32/wave
    float4v acc[4][2];
#pragma unroll
    for (int i = 0; i < 4; i++)
#pragma unroll
      for (int j = 0; j < 2; j++) acc[i][j] = (float4v){0.f, 0.f, 0.f, 0.f};
    float4 pf0[2], pf1[2];
    auto ldu = [&](int j, int k0) {
      int u = tid + j * 512;
      const float4* p;
      if (u < 512) { int row = u >> 2, q = u & 3;
        p = (const float4*)(seq + (size_t)(m0 + row) * DIN + k0 + q * 8);
      } else { int v = u - 512; int row = v >> 2, q = v & 3;
        p = (const float4*)(Win + (size_t)(n0 + row) * DIN + k0 + q * 8);
      }
      pf0[j] = p[0]; pf1[j] = p[1];
    };
    auto stu = [&](int j) {
      int u = tid + j * 512;
      short8 s = pack8(pf0[j], pf1[j]);
      if (u < 512) { int row = u >> 2, q = u & 3; *(short8*)&sm.g1.As[row * 40 + q * 8] = s; }
      else { int v = u - 512; int row = v >> 2, q = v & 3; *(short8*)&sm.g1.Bs[row * 40 + q * 8] = s; }
    };
    ldu(0, 0); ldu(1, 0);
    for (int k0 = 0; k0 < DIN; k0 += 32) {
      stu(0); stu(1);
      __syncthreads();
      if (k0 + 32 < DIN) { ldu(0, k0 + 32); ldu(1, k0 + 32); }   // overlap MFMAs
      short8 afr[4], bfr[2];
#pragma unroll
      for (int mi = 0; mi < 4; mi++)
        afr[mi] = *(const short8*)&sm.g1.As[(wm * 64 + mi * 16 + r16) * 40 + quad * 8];
#pragma unroll
      for (int ni = 0; ni < 2; ni++)
        bfr[ni] = *(const short8*)&sm.g1.Bs[(wn * 32 + ni * 16 + r16) * 40 + quad * 8];
#pragma unroll
      for (int mi = 0; mi < 4; mi++)
#pragma unroll
        for (int ni = 0; ni < 2; ni++)
          acc[mi][ni] = __builtin_amdgcn_mfma_f32_16x16x32_bf16(afr[mi], bfr[ni], acc[mi][ni], 0, 0, 0);
      __syncthreads();
    }
#pragma unroll
    for (int mi = 0; mi < 4; mi++)
#pragma unroll
      for (int ni = 0; ni < 2; ni++)
#pragma unroll
        for (int r = 0; r < 4; r++)
          ab[(size_t)(m0 + wm * 64 + mi * 16 + quad * 4 + r) * (2 * DM)
             + n0 + wn * 32 + ni * 16 + r16] = acc[mi][ni][r];
  }
  grid_barrier(bar + 0, NBLK);

  // ===== Phase 2: per 16-row tile: x=silu(conv(ab)); proj -> Bm/Cm/t1; delta =====
  if (blk < 128) {
    const int m0 = blk * 16;
    const int bq = m0 >> 10;
    float4v accp = (float4v){0.f, 0.f, 0.f, 0.f};
    for (int k0 = 0; k0 < DM; k0 += 32) {
      if (tid < 64) {                       // stage x frag (16 rows x 32 cols)
        int row = tid >> 2, q = tid & 3;
        int n = m0 + row, l = n & (L_ - 1);
        float4 tap0[KER_], tap1[KER_];
#pragma unroll
        for (int t = 0; t < KER_; t++) {
          int ll = l - (KER_ - 1) + t;
          if (ll >= 0) {
            const float4* p = (const float4*)(ab + (size_t)(bq * L_ + ll) * (2 * DM) + k0 + q * 8);
            tap0[t] = p[0]; tap1[t] = p[1];
          } else { tap0[t] = float4{0.f,0.f,0.f,0.f}; tap1[t] = float4{0.f,0.f,0.f,0.f}; }
        }
        float r8[8];
#pragma unroll
        for (int e = 0; e < 8; e++) {
          int d = k0 + q * 8 + e;
          float4 w = *(const float4*)(cw + d * 4);
          float a = cb[d];
#pragma unroll
          for (int t = 0; t < KER_; t++) {
            float te = (e < 4) ? (&tap0[t].x)[e] : (&tap1[t].x)[e - 4];
            a += te * (&w.x)[t];
          }
          r8[e] = silu_f(a);
        }
        *(short8*)&sm.pj.xs[row * 40 + q * 8] =
            pack8(float4{r8[0], r8[1], r8[2], r8[3]}, float4{r8[4], r8[5], r8[6], r8[7]});
      } else if (tid < 448) {               // stage Wcat frag (96 rows x 32 cols)
        int t2 = tid - 64, row = t2 >> 2, q = t2 & 3;
        const float* bp = (row < 16) ? (WB + (size_t)row * DM)
                        : (row < 32) ? (WC + (size_t)(row - 16) * DM)
                                     : (WD1 + (size_t)(row - 32) * DM);
        const float4* p = (const float4*)(bp + k0 + q * 8);
        *(short8*)&sm.pj.wsb[row * 40 + q * 8] = pack8(p[0], p[1]);
      }
      __syncthreads();
      if (wave < 6) {
        short8 afr = *(const short8*)&sm.pj.xs[r16 * 40 + quad * 8];
        short8 bfr = *(const short8*)&sm.pj.wsb[(wave * 16 + r16) * 40 + quad * 8];
        accp = __builtin_amdgcn_mfma_f32_16x16x32_bf16(afr, bfr, accp, 0, 0, 0);
      }
      __syncthreads();
    }
    if (wave < 6) {                         // Bm/Cm -> global; t1 -> LDS bf16
      int gl = wave * 16 + r16;             // 0..95
#pragma unroll
      for (int r = 0; r < 4; r++) {
        int lr = quad * 4 + r;
        float v = accp[r];
        if (gl < 32) pall[(size_t)(m0 + lr) * 96 + gl] = v;
        else         sm.pj.t1s[lr * 72 + (gl - 32)] = f2bf1(v);
      }
    }
    __syncthreads();
    // delta: dlt[16,1024] = softplus(t1 . WD2^T + Dv); wave owns 128 cols
    for (int cb2 = 0; cb2 < 8; cb2++) {
      int n0d = wave * 128 + cb2 * 16;
      float4v accd = (float4v){0.f, 0.f, 0.f, 0.f};
#pragma unroll
      for (int ks = 0; ks < DD; ks += 32) {
        short8 afr = *(const short8*)&sm.pj.t1s[r16 * 72 + ks + quad * 8];
        const float4* p = (const float4*)(WD2 + (size_t)(n0d + r16) * DD + ks + quad * 8);
        short8 bfr = pack8(p[0], p[1]);
        accd = __builtin_amdgcn_mfma_f32_16x16x32_bf16(afr, bfr, accd, 0, 0, 0);
      }
      int gn = n0d + r16;
      float dvn = Dv[gn];
#pragma unroll
      for (int r = 0; r < 4; r++) {
        float v = accd[r] + dvn;
        v = fmaxf(v, 0.f) + log1pf(expf(-fabsf(v)));   // stable softplus
        dlt[(size_t)(m0 + quad * 4 + r) * DM + gn] = v;
      }
    }
  }
  grid_barrier(bar + 1, NBLK);

  // ================= Phase 3: fused selective scan (round-6 logic) =========
  {
    const int b   = blk >> 7;
    const int d0  = (blk & 127) * SD;
    const bool act = tid < 256;
    const int dd  = tid & (SD - 1);
    const int c   = (tid >> 3) & 31;
    const int d   = d0 + dd;
    float e[DS], h[DS], p[DS];
    float4 w = {0.f,0.f,0.f,0.f};
    float cbv = 0.f, Dd = 0.f;
    const int lbase = c * SLC;
    const int nbase = b * L_ + lbase;
    if (act) {
#pragma unroll
      for (int s = 0; s < DS; s++) e[s] = expf(-Aa[d * DS + s]);
      w = *(const float4*)(cw + d * 4);
      cbv = cb[d];
      Dd  = Dv[d];
    }
    auto abA = [&](int l) -> float {
      return (l >= 0) ? ab[(size_t)(b * L_ + l) * (2 * DM) + d] : 0.f;
    };
    if (act) {
      float r0 = abA(lbase - 3), r1 = abA(lbase - 2), r2 = abA(lbase - 1);
#pragma unroll
      for (int s = 0; s < DS; s++) { h[s] = 0.f; p[s] = 1.f; }
      for (int i = 0; i < SLC; i++) {
        int n = nbase + i;
        float a3 = ab[(size_t)n * (2 * DM) + d];
        float xv = silu_f(cbv + r0 * w.x + r1 * w.y + r2 * w.z + a3 * w.w);
        r0 = r1; r1 = r2; r2 = a3;
        float dl = dlt[(size_t)n * DM + d];
        float dx = dl * xv;
        const float4* bm4 = (const float4*)(pall + (size_t)n * 96);
        float4 b0 = bm4[0], b1 = bm4[1], b2 = bm4[2], b3 = bm4[3];
        float bmv[DS] = { b0.x,b0.y,b0.z,b0.w, b1.x,b1.y,b1.z,b1.w,
                          b2.x,b2.y,b2.z,b2.w, b3.x,b3.y,b3.z,b3.w };
#pragma unroll
        for (int s = 0; s < DS; s++) {
          float a_ = e[s] * dl;
          h[s] = a_ * h[s] + bmv[s] * dx;
          p[s] *= a_;
        }
      }
#pragma unroll
      for (int s = 0; s < DS; s++) { sm.sc.Pl[c][s][dd] = p[s]; sm.sc.Hl[c][s][dd] = h[s]; }
    }
    __syncthreads();
    if (tid < DS * SD) {
      int s2  = tid >> 3;
      int dd2 = tid & (SD - 1);
      float H = 0.f;
      for (int c2 = 0; c2 < SC; c2++) {
        float pp = sm.sc.Pl[c2][s2][dd2];
        float hh = sm.sc.Hl[c2][s2][dd2];
        sm.sc.Pl[c2][s2][dd2] = H;
        H = pp * H + hh;
      }
    }
    __syncthreads();
    if (act) {
#pragma unroll
      for (int s = 0; s < DS; s++) h[s] = sm.sc.Pl[c][s][dd];
      float r0 = abA(lbase - 3), r1 = abA(lbase - 2), r2 = abA(lbase - 1);
      for (int i = 0; i < SLC; i++) {
        int n = nbase + i;
        float a3 = ab[(size_t)n * (2 * DM) + d];
        float xv = silu_f(cbv + r0 * w.x + r1 * w.y + r2 * w.z + a3 * w.w);
        r0 = r1; r1 = r2; r2 = a3;
        float dl = dlt[(size_t)n * DM + d];
        float dx = dl * xv;
        const float4* bm4 = (const float4*)(pall + (size_t)n * 96);
        float4 b0 = bm4[0], b1 = bm4[1], b2 = bm4[2], b3 = bm4[3];
        float4 c0 = bm4[4], c1 = bm4[5], c2v = bm4[6], c3 = bm4[7];
        float bmv[DS] = { b0.x,b0.y,b0.z,b0.w, b1.x,b1.y,b1.z,b1.w,
                          b2.x,b2.y,b2.z,b2.w, b3.x,b3.y,b3.z,b3.w };
        float cmv[DS] = { c0.x,c0.y,c0.z,c0.w, c1.x,c1.y,c1.z,c1.w,
                          c2v.x,c2v.y,c2v.z,c2v.w, c3.x,c3.y,c3.z,c3.w };
        float y = 0.f;
#pragma unroll
        for (int s = 0; s < DS; s++) {
          h[s] = e[s] * dl * h[s] + bmv[s] * dx;
          y += h[s] * cmv[s];
        }
        y += Dd * xv;
        float g = ab[(size_t)n * (2 * DM) + DM + d];
        sout[(size_t)n * DM + d] = y * silu_f(g);
      }
    }
  }
  grid_barrier(bar + 2, NBLK);

  // ================= Phase 4: out[2048,512] = sout . Wout^T ================
  {
    const int m0 = (blk >> 3) * 64;
    const int n0 = (blk & 7) * 64;
    const int wm = wave & 1, wn = wave >> 1;   // 2 x 4 waves, tile 32x16/wave
    float4v acc[2];
    acc[0] = (float4v){0.f, 0.f, 0.f, 0.f};
    acc[1] = (float4v){0.f, 0.f, 0.f, 0.f};
    float4 pf0, pf1;
    auto ldu = [&](int k0) {
      const float4* p;
      if (tid < 256) { int row = tid >> 2, q = tid & 3;
        p = (const float4*)(sout + (size_t)(m0 + row) * DM + k0 + q * 8);
      } else { int v = tid - 256; int row = v >> 2, q = v & 3;
        p = (const float4*)(Wout + (size_t)(n0 + row) * DM + k0 + q * 8);
      }
      pf0 = p[0]; pf1 = p[1];
    };
    auto stu = [&]() {
      short8 s = pack8(pf0, pf1);
      if (tid < 256) { int row = tid >> 2, q = tid & 3; *(short8*)&sm.g2.As[row * 40 + q * 8] = s; }
      else { int v = tid - 256; int row = v >> 2, q = v & 3; *(short8*)&sm.g2.Bs[row * 40 + q * 8] = s; }
    };
    ldu(0);
    for (int k0 = 0; k0 < DM; k0 += 32) {
      stu();
      __syncthreads();
      if (k0 + 32 < DM) ldu(k0 + 32);
      short8 afr[2], bfr;
      afr[0] = *(const short8*)&sm.g2.As[(wm * 32 + r16) * 40 + quad * 8];
      afr[1] = *(const short8*)&sm.g2.As[(wm * 32 + 16 + r16) * 40 + quad * 8];
      bfr    = *(const short8*)&sm.g2.Bs[(wn * 16 + r16) * 40 + quad * 8];
      acc[0] = __builtin_amdgcn_mfma_f32_16x16x32_bf16(afr[0], bfr, acc[0], 0, 0, 0);
      acc[1] = __builtin_amdgcn_mfma_f32_16x16x32_bf16(afr[1], bfr, acc[1], 0, 0, 0);
      __syncthreads();
    }
#pragma unroll
    for (int mi = 0; mi < 2; mi++)
#pragma unroll
      for (int r = 0; r < 4; r++)
        out[(size_t)(m0 + wm * 32 + mi * 16 + quad * 4 + r) * DIN + n0 + wn * 16 + r16] = acc[mi][r];
  }
}

// ---------------------------------------------------------------------------
extern "C" void kernel_launch(void* const* d_in, const int* in_sizes, int n_in,
                              void* d_out, int out_size, void* d_ws, size_t ws_size,
                              hipStream_t stream) {
  const float* seq  = (const float*)d_in[0];
  const float* Win  = (const float*)d_in[1];
  const float* Wout = (const float*)d_in[2];
  const float* WB   = (const float*)d_in[3];
  const float* WC   = (const float*)d_in[4];
  const float* WD1  = (const float*)d_in[5];
  const float* WD2  = (const float*)d_in[6];
  const float* cw   = (const float*)d_in[7];
  const float* cb   = (const float*)d_in[8];
  const float* A    = (const float*)d_in[9];
  const float* Dv   = (const float*)d_in[10];
  float* out = (float*)d_out;

  float* ws   = (float*)d_ws;
  float* ab   = ws;                   // 2048*2048 = 4194304
  float* dlt  = ab   + 4194304;       // 2048*1024 = 2097152
  float* pall = dlt  + 2097152;       // 2048*96   = 196608  (Bm|Cm)
  float* sout = pall + 196608;        // 2097152
  unsigned* bar = (unsigned*)(sout + 2097152);   // 3 barrier counters
  // total ~34.3 MB + 64 B

  hipMemsetAsync(bar, 0, 64, stream);
  mega_k<<<NBLK, NTHR, 0, stream>>>(seq, Win, Wout, WB, WC, WD1, WD2, cw, cb,
                                    A, Dv, out, ab, dlt, pall, sout, bar);
}

// Round 8
// 223.216 us; speedup vs baseline: 2.1081x; 2.1081x over previous
//
#include <hip/hip_runtime.h>
#include <hip/hip_bf16.h>

typedef short short8 __attribute__((ext_vector_type(8)));
typedef float float4v __attribute__((ext_vector_type(4)));

#define B_   2
#define L_   1024
#define DIN  512
#define DM   1024
#define DS   16
#define DD   64
#define KER_ 4
#define NROW (B_*L_)     // 2048

// scan geometry: block = (b, 8 d-lanes); 32 chunks x 32 steps = L
#define SD   8
#define SC   32
#define SLC  32
#define SDP  9

__device__ __forceinline__ float silu_f(float v){ return v / (1.f + expf(-v)); }

// packed f32x2 -> bf16x2 RNE (v_cvt_pk_bf16_f32)
__device__ __forceinline__ short2 f2bf2(float a, float b) {
  __hip_bfloat162 h = __float22bfloat162_rn(float2{a, b});
  union { __hip_bfloat162 h; short2 s; } u; u.h = h; return u.s;
}
__device__ __forceinline__ short f2bf1(float a) {
  __hip_bfloat16 h = __float2bfloat16(a);
  union { __hip_bfloat16 h; short s; } u; u.h = h; return u.s;
}
__device__ __forceinline__ short8 pack8(const float4& x0, const float4& x1) {
  short2 s0 = f2bf2(x0.x, x0.y), s1 = f2bf2(x0.z, x0.w);
  short2 s2 = f2bf2(x1.x, x1.y), s3 = f2bf2(x1.z, x1.w);
  return short8{ s0.x, s0.y, s1.x, s1.y, s2.x, s2.y, s3.x, s3.y };
}

// ---------------------------------------------------------------------------
// GEMM1: ab[2048,2048] = seq[2048,512] . Win[2048,512]^T
// 512 thr = 8 waves (2x4), BM=BN=128, wave tile 64x32, BK=32, reg-prefetch.
// ---------------------------------------------------------------------------
__global__ __launch_bounds__(512)
void gemm1_k(const float* __restrict__ seq, const float* __restrict__ Win,
             float* __restrict__ ab) {
  __shared__ short As[128 * 40];
  __shared__ short Bs[128 * 40];
  const int tid  = threadIdx.x;
  const int lane = tid & 63;
  const int wave = tid >> 6;
  const int r16  = lane & 15;
  const int quad = lane >> 4;
  const int m0 = blockIdx.y * 128;
  const int n0 = blockIdx.x * 128;
  const int wm = wave & 1, wn = wave >> 1;
  float4v acc[4][2];
#pragma unroll
  for (int i = 0; i < 4; i++)
#pragma unroll
    for (int j = 0; j < 2; j++) acc[i][j] = (float4v){0.f, 0.f, 0.f, 0.f};
  float4 pf0[2], pf1[2];
  auto ldu = [&](int j, int k0) {
    int u = tid + j * 512;
    const float4* p;
    if (u < 512) { int row = u >> 2, q = u & 3;
      p = (const float4*)(seq + (size_t)(m0 + row) * DIN + k0 + q * 8);
    } else { int v = u - 512; int row = v >> 2, q = v & 3;
      p = (const float4*)(Win + (size_t)(n0 + row) * DIN + k0 + q * 8);
    }
    pf0[j] = p[0]; pf1[j] = p[1];
  };
  auto stu = [&](int j) {
    int u = tid + j * 512;
    short8 s = pack8(pf0[j], pf1[j]);
    if (u < 512) { int row = u >> 2, q = u & 3; *(short8*)&As[row * 40 + q * 8] = s; }
    else { int v = u - 512; int row = v >> 2, q = v & 3; *(short8*)&Bs[row * 40 + q * 8] = s; }
  };
  ldu(0, 0); ldu(1, 0);
  for (int k0 = 0; k0 < DIN; k0 += 32) {
    stu(0); stu(1);
    __syncthreads();
    if (k0 + 32 < DIN) { ldu(0, k0 + 32); ldu(1, k0 + 32); }   // overlap MFMAs
    short8 afr[4], bfr[2];
#pragma unroll
    for (int mi = 0; mi < 4; mi++)
      afr[mi] = *(const short8*)&As[(wm * 64 + mi * 16 + r16) * 40 + quad * 8];
#pragma unroll
    for (int ni = 0; ni < 2; ni++)
      bfr[ni] = *(const short8*)&Bs[(wn * 32 + ni * 16 + r16) * 40 + quad * 8];
#pragma unroll
    for (int mi = 0; mi < 4; mi++)
#pragma unroll
      for (int ni = 0; ni < 2; ni++)
        acc[mi][ni] = __builtin_amdgcn_mfma_f32_16x16x32_bf16(afr[mi], bfr[ni], acc[mi][ni], 0, 0, 0);
    __syncthreads();
  }
#pragma unroll
  for (int mi = 0; mi < 4; mi++)
#pragma unroll
    for (int ni = 0; ni < 2; ni++)
#pragma unroll
      for (int r = 0; r < 4; r++)
        ab[(size_t)(m0 + wm * 64 + mi * 16 + quad * 4 + r) * (2 * DM)
           + n0 + wn * 32 + ni * 16 + r16] = acc[mi][ni][r];
}

// ---------------------------------------------------------------------------
// proj+delta fused, one block per 16 rows (128 blocks, 512 thr).
// x = silu(conv(ab)) staged in-flight; proj -> Bm/Cm (global) + t1 (LDS bf16);
// delta = softplus(t1 . WD2^T + Dv) consumed straight from LDS.
// ---------------------------------------------------------------------------
__global__ __launch_bounds__(512)
void proj_delta_k(const float* __restrict__ ab, const float* __restrict__ WB,
                  const float* __restrict__ WC, const float* __restrict__ WD1,
                  const float* __restrict__ WD2, const float* __restrict__ cw,
                  const float* __restrict__ cb, const float* __restrict__ Dv,
                  float* __restrict__ pall, float* __restrict__ dlt) {
  __shared__ short xs[16 * 40];
  __shared__ short wsb[96 * 40];
  __shared__ short t1s[16 * 72];
  const int tid  = threadIdx.x;
  const int lane = tid & 63;
  const int wave = tid >> 6;
  const int r16  = lane & 15;
  const int quad = lane >> 4;
  const int m0 = blockIdx.x * 16;
  const int bq = m0 >> 10;
  float4v accp = (float4v){0.f, 0.f, 0.f, 0.f};
  for (int k0 = 0; k0 < DM; k0 += 32) {
    if (tid < 64) {                       // stage x frag (16 rows x 32 cols)
      int row = tid >> 2, q = tid & 3;
      int n = m0 + row, l = n & (L_ - 1);
      float4 tap0[KER_], tap1[KER_];
#pragma unroll
      for (int t = 0; t < KER_; t++) {
        int ll = l - (KER_ - 1) + t;
        if (ll >= 0) {
          const float4* p = (const float4*)(ab + (size_t)(bq * L_ + ll) * (2 * DM) + k0 + q * 8);
          tap0[t] = p[0]; tap1[t] = p[1];
        } else { tap0[t] = float4{0.f,0.f,0.f,0.f}; tap1[t] = float4{0.f,0.f,0.f,0.f}; }
      }
      float r8[8];
#pragma unroll
      for (int e = 0; e < 8; e++) {
        int d = k0 + q * 8 + e;
        float4 w = *(const float4*)(cw + d * 4);
        float a = cb[d];
#pragma unroll
        for (int t = 0; t < KER_; t++) {
          float te = (e < 4) ? (&tap0[t].x)[e] : (&tap1[t].x)[e - 4];
          a += te * (&w.x)[t];
        }
        r8[e] = silu_f(a);
      }
      *(short8*)&xs[row * 40 + q * 8] =
          pack8(float4{r8[0], r8[1], r8[2], r8[3]}, float4{r8[4], r8[5], r8[6], r8[7]});
    } else if (tid < 448) {               // stage Wcat frag (96 rows x 32 cols)
      int t2 = tid - 64, row = t2 >> 2, q = t2 & 3;
      const float* bp = (row < 16) ? (WB + (size_t)row * DM)
                      : (row < 32) ? (WC + (size_t)(row - 16) * DM)
                                   : (WD1 + (size_t)(row - 32) * DM);
      const float4* p = (const float4*)(bp + k0 + q * 8);
      *(short8*)&wsb[row * 40 + q * 8] = pack8(p[0], p[1]);
    }
    __syncthreads();
    if (wave < 6) {
      short8 afr = *(const short8*)&xs[r16 * 40 + quad * 8];
      short8 bfr = *(const short8*)&wsb[(wave * 16 + r16) * 40 + quad * 8];
      accp = __builtin_amdgcn_mfma_f32_16x16x32_bf16(afr, bfr, accp, 0, 0, 0);
    }
    __syncthreads();
  }
  if (wave < 6) {                         // Bm/Cm -> global; t1 -> LDS bf16
    int gl = wave * 16 + r16;             // 0..95
#pragma unroll
    for (int r = 0; r < 4; r++) {
      int lr = quad * 4 + r;
      float v = accp[r];
      if (gl < 32) pall[(size_t)(m0 + lr) * 96 + gl] = v;
      else         t1s[lr * 72 + (gl - 32)] = f2bf1(v);
    }
  }
  __syncthreads();
  // delta: dlt[16,1024] = softplus(t1 . WD2^T + Dv); each wave owns 128 cols
  for (int cb2 = 0; cb2 < 8; cb2++) {
    int n0d = wave * 128 + cb2 * 16;
    float4v accd = (float4v){0.f, 0.f, 0.f, 0.f};
#pragma unroll
    for (int ks = 0; ks < DD; ks += 32) {
      short8 afr = *(const short8*)&t1s[r16 * 72 + ks + quad * 8];
      const float4* p = (const float4*)(WD2 + (size_t)(n0d + r16) * DD + ks + quad * 8);
      short8 bfr = pack8(p[0], p[1]);
      accd = __builtin_amdgcn_mfma_f32_16x16x32_bf16(afr, bfr, accd, 0, 0, 0);
    }
    int gn = n0d + r16;
    float dvn = Dv[gn];
#pragma unroll
    for (int r = 0; r < 4; r++) {
      float v = accd[r] + dvn;
      v = fmaxf(v, 0.f) + log1pf(expf(-fabsf(v)));   // stable softplus
      dlt[(size_t)(m0 + quad * 4 + r) * DM + gn] = v;
    }
  }
}

// ---------------------------------------------------------------------------
// Fused selective scan (round-6 verified). Block = (b, 8 d-lanes); chunk
// combine is LDS-local; x recomputed via rolling conv window.
// ---------------------------------------------------------------------------
__global__ __launch_bounds__(256)
void scan_fused_k(const float* __restrict__ ab, const float* __restrict__ dlt,
                  const float* __restrict__ pall, const float* __restrict__ A,
                  const float* __restrict__ Dv, const float* __restrict__ cw,
                  const float* __restrict__ cb, float* __restrict__ sout) {
  __shared__ float Pl[SC][DS][SDP];
  __shared__ float Hl[SC][DS][SDP];
  const int blk = blockIdx.x;
  const int b   = blk >> 7;
  const int d0  = (blk & 127) * SD;
  const int dd  = threadIdx.x & (SD - 1);
  const int c   = threadIdx.x >> 3;
  const int d   = d0 + dd;

  float e[DS];
#pragma unroll
  for (int s = 0; s < DS; s++) e[s] = expf(-A[d * DS + s]);
  const int   lbase = c * SLC;
  const int   nbase = b * L_ + lbase;
  const float4 w    = *(const float4*)(cw + d * 4);
  const float  cbv  = cb[d];

  auto abA = [&](int l) -> float {
    return (l >= 0) ? ab[(size_t)(b * L_ + l) * (2 * DM) + d] : 0.f;
  };

  float r0 = abA(lbase - 3), r1 = abA(lbase - 2), r2 = abA(lbase - 1);
  float h[DS], p[DS];
#pragma unroll
  for (int s = 0; s < DS; s++) { h[s] = 0.f; p[s] = 1.f; }
  for (int i = 0; i < SLC; i++) {
    int n = nbase + i;
    float a3 = ab[(size_t)n * (2 * DM) + d];
    float xv = silu_f(cbv + r0 * w.x + r1 * w.y + r2 * w.z + a3 * w.w);
    r0 = r1; r1 = r2; r2 = a3;
    float dl = dlt[(size_t)n * DM + d];
    float dx = dl * xv;
    const float4* bm4 = (const float4*)(pall + (size_t)n * 96);
    float4 b0 = bm4[0], b1 = bm4[1], b2 = bm4[2], b3 = bm4[3];
    float bmv[DS] = { b0.x,b0.y,b0.z,b0.w, b1.x,b1.y,b1.z,b1.w,
                      b2.x,b2.y,b2.z,b2.w, b3.x,b3.y,b3.z,b3.w };
#pragma unroll
    for (int s = 0; s < DS; s++) {
      float a_ = e[s] * dl;
      h[s] = a_ * h[s] + bmv[s] * dx;
      p[s] *= a_;
    }
  }
#pragma unroll
  for (int s = 0; s < DS; s++) { Pl[c][s][dd] = p[s]; Hl[c][s][dd] = h[s]; }
  __syncthreads();

  if (threadIdx.x < DS * SD) {
    int s2  = threadIdx.x >> 3;
    int dd2 = threadIdx.x & (SD - 1);
    float H = 0.f;
    for (int c2 = 0; c2 < SC; c2++) {
      float pp = Pl[c2][s2][dd2];
      float hh = Hl[c2][s2][dd2];
      Pl[c2][s2][dd2] = H;
      H = pp * H + hh;
    }
  }
  __syncthreads();

#pragma unroll
  for (int s = 0; s < DS; s++) h[s] = Pl[c][s][dd];
  float Dd = Dv[d];
  r0 = abA(lbase - 3); r1 = abA(lbase - 2); r2 = abA(lbase - 1);
  for (int i = 0; i < SLC; i++) {
    int n = nbase + i;
    float a3 = ab[(size_t)n * (2 * DM) + d];
    float xv = silu_f(cbv + r0 * w.x + r1 * w.y + r2 * w.z + a3 * w.w);
    r0 = r1; r1 = r2; r2 = a3;
    float dl = dlt[(size_t)n * DM + d];
    float dx = dl * xv;
    const float4* bm4 = (const float4*)(pall + (size_t)n * 96);
    float4 b0 = bm4[0], b1 = bm4[1], b2 = bm4[2], b3 = bm4[3];
    float4 c0 = bm4[4], c1 = bm4[5], c2v = bm4[6], c3 = bm4[7];
    float bmv[DS] = { b0.x,b0.y,b0.z,b0.w, b1.x,b1.y,b1.z,b1.w,
                      b2.x,b2.y,b2.z,b2.w, b3.x,b3.y,b3.z,b3.w };
    float cmv[DS] = { c0.x,c0.y,c0.z,c0.w, c1.x,c1.y,c1.z,c1.w,
                      c2v.x,c2v.y,c2v.z,c2v.w, c3.x,c3.y,c3.z,c3.w };
    float y = 0.f;
#pragma unroll
    for (int s = 0; s < DS; s++) {
      h[s] = e[s] * dl * h[s] + bmv[s] * dx;
      y += h[s] * cmv[s];
    }
    y += Dd * xv;
    float g = ab[(size_t)n * (2 * DM) + DM + d];
    sout[(size_t)n * DM + d] = y * silu_f(g);
  }
}

// ---------------------------------------------------------------------------
// GEMM2: out[2048,512] = sout[2048,1024] . Wout[512,1024]^T
// 512 thr = 8 waves (2x4), BM=BN=64, wave tile 32x16, full K.
// ---------------------------------------------------------------------------
__global__ __launch_bounds__(512)
void gemm2_k(const float* __restrict__ sout, const float* __restrict__ Wout,
             float* __restrict__ out) {
  __shared__ short As[64 * 40];
  __shared__ short Bs[64 * 40];
  const int tid  = threadIdx.x;
  const int lane = tid & 63;
  const int wave = tid >> 6;
  const int r16  = lane & 15;
  const int quad = lane >> 4;
  const int m0 = blockIdx.y * 64;
  const int n0 = blockIdx.x * 64;
  const int wm = wave & 1, wn = wave >> 1;
  float4v acc[2];
  acc[0] = (float4v){0.f, 0.f, 0.f, 0.f};
  acc[1] = (float4v){0.f, 0.f, 0.f, 0.f};
  float4 pf0, pf1;
  auto ldu = [&](int k0) {
    const float4* p;
    if (tid < 256) { int row = tid >> 2, q = tid & 3;
      p = (const float4*)(sout + (size_t)(m0 + row) * DM + k0 + q * 8);
    } else { int v = tid - 256; int row = v >> 2, q = v & 3;
      p = (const float4*)(Wout + (size_t)(n0 + row) * DM + k0 + q * 8);
    }
    pf0 = p[0]; pf1 = p[1];
  };
  auto stu = [&]() {
    short8 s = pack8(pf0, pf1);
    if (tid < 256) { int row = tid >> 2, q = tid & 3; *(short8*)&As[row * 40 + q * 8] = s; }
    else { int v = tid - 256; int row = v >> 2, q = v & 3; *(short8*)&Bs[row * 40 + q * 8] = s; }
  };
  ldu(0);
  for (int k0 = 0; k0 < DM; k0 += 32) {
    stu();
    __syncthreads();
    if (k0 + 32 < DM) ldu(k0 + 32);
    short8 afr[2], bfr;
    afr[0] = *(const short8*)&As[(wm * 32 + r16) * 40 + quad * 8];
    afr[1] = *(const short8*)&As[(wm * 32 + 16 + r16) * 40 + quad * 8];
    bfr    = *(const short8*)&Bs[(wn * 16 + r16) * 40 + quad * 8];
    acc[0] = __builtin_amdgcn_mfma_f32_16x16x32_bf16(afr[0], bfr, acc[0], 0, 0, 0);
    acc[1] = __builtin_amdgcn_mfma_f32_16x16x32_bf16(afr[1], bfr, acc[1], 0, 0, 0);
    __syncthreads();
  }
#pragma unroll
  for (int mi = 0; mi < 2; mi++)
#pragma unroll
    for (int r = 0; r < 4; r++)
      out[(size_t)(m0 + wm * 32 + mi * 16 + quad * 4 + r) * DIN + n0 + wn * 16 + r16] = acc[mi][r];
}

// ---------------------------------------------------------------------------
extern "C" void kernel_launch(void* const* d_in, const int* in_sizes, int n_in,
                              void* d_out, int out_size, void* d_ws, size_t ws_size,
                              hipStream_t stream) {
  const float* seq  = (const float*)d_in[0];
  const float* Win  = (const float*)d_in[1];
  const float* Wout = (const float*)d_in[2];
  const float* WB   = (const float*)d_in[3];
  const float* WC   = (const float*)d_in[4];
  const float* WD1  = (const float*)d_in[5];
  const float* WD2  = (const float*)d_in[6];
  const float* cw   = (const float*)d_in[7];
  const float* cb   = (const float*)d_in[8];
  const float* A    = (const float*)d_in[9];
  const float* Dv   = (const float*)d_in[10];
  float* out = (float*)d_out;

  float* ws   = (float*)d_ws;
  float* ab   = ws;                   // 2048*2048 = 4194304
  float* dlt  = ab   + 4194304;       // 2048*1024 = 2097152
  float* pall = dlt  + 2097152;       // 2048*96   = 196608  (Bm|Cm)
  float* sout = pall + 196608;        // 2097152
  // total 34.3 MB

  gemm1_k<<<dim3(16, 16), 512, 0, stream>>>(seq, Win, ab);
  proj_delta_k<<<128, 512, 0, stream>>>(ab, WB, WC, WD1, WD2, cw, cb, Dv, pall, dlt);
  scan_fused_k<<<B_ * (DM / SD), 256, 0, stream>>>(ab, dlt, pall, A, Dv, cw, cb, sout);
  gemm2_k<<<dim3(8, 32), 512, 0, stream>>>(sout, Wout, out);
}

// Round 9
// 179.060 us; speedup vs baseline: 2.6280x; 1.2466x over previous
//
#include <hip/hip_runtime.h>
#include <hip/hip_bf16.h>

typedef short short8 __attribute__((ext_vector_type(8)));
typedef float float4v __attribute__((ext_vector_type(4)));

#define B_   2
#define L_   1024
#define DIN  512
#define DM   1024
#define DS   16
#define DD   64
#define KER_ 4
#define NROW (B_*L_)     // 2048

// scan geometry: block = (b, 8 d-lanes); 32 chunks x 32 steps = L
#define SD   8
#define SC   32
#define SLC  32
#define SDP  9

__device__ __forceinline__ float silu_f(float v){ return v / (1.f + expf(-v)); }

// packed f32x2 -> bf16x2 RNE (v_cvt_pk_bf16_f32)
__device__ __forceinline__ short2 f2bf2(float a, float b) {
  __hip_bfloat162 h = __float22bfloat162_rn(float2{a, b});
  union { __hip_bfloat162 h; short2 s; } u; u.h = h; return u.s;
}
__device__ __forceinline__ short8 pack8(const float4& x0, const float4& x1) {
  short2 s0 = f2bf2(x0.x, x0.y), s1 = f2bf2(x0.z, x0.w);
  short2 s2 = f2bf2(x1.x, x1.y), s3 = f2bf2(x1.z, x1.w);
  return short8{ s0.x, s0.y, s1.x, s1.y, s2.x, s2.y, s3.x, s3.y };
}

// ---------------------------------------------------------------------------
// GEMM1: ab[2048,2048] = seq[2048,512] . Win[2048,512]^T
// 512 thr = 8 waves (2x4), BM=BN=128, wave tile 64x32, BK=32, reg-prefetch.
// ---------------------------------------------------------------------------
__global__ __launch_bounds__(512)
void gemm1_k(const float* __restrict__ seq, const float* __restrict__ Win,
             float* __restrict__ ab) {
  __shared__ short As[128 * 40];
  __shared__ short Bs[128 * 40];
  const int tid  = threadIdx.x;
  const int lane = tid & 63;
  const int wave = tid >> 6;
  const int r16  = lane & 15;
  const int quad = lane >> 4;
  const int m0 = blockIdx.y * 128;
  const int n0 = blockIdx.x * 128;
  const int wm = wave & 1, wn = wave >> 1;
  float4v acc[4][2];
#pragma unroll
  for (int i = 0; i < 4; i++)
#pragma unroll
    for (int j = 0; j < 2; j++) acc[i][j] = (float4v){0.f, 0.f, 0.f, 0.f};
  float4 pf0[2], pf1[2];
  auto ldu = [&](int j, int k0) {
    int u = tid + j * 512;
    const float4* p;
    if (u < 512) { int row = u >> 2, q = u & 3;
      p = (const float4*)(seq + (size_t)(m0 + row) * DIN + k0 + q * 8);
    } else { int v = u - 512; int row = v >> 2, q = v & 3;
      p = (const float4*)(Win + (size_t)(n0 + row) * DIN + k0 + q * 8);
    }
    pf0[j] = p[0]; pf1[j] = p[1];
  };
  auto stu = [&](int j) {
    int u = tid + j * 512;
    short8 s = pack8(pf0[j], pf1[j]);
    if (u < 512) { int row = u >> 2, q = u & 3; *(short8*)&As[row * 40 + q * 8] = s; }
    else { int v = u - 512; int row = v >> 2, q = v & 3; *(short8*)&Bs[row * 40 + q * 8] = s; }
  };
  ldu(0, 0); ldu(1, 0);
  for (int k0 = 0; k0 < DIN; k0 += 32) {
    stu(0); stu(1);
    __syncthreads();
    if (k0 + 32 < DIN) { ldu(0, k0 + 32); ldu(1, k0 + 32); }   // overlap MFMAs
    short8 afr[4], bfr[2];
#pragma unroll
    for (int mi = 0; mi < 4; mi++)
      afr[mi] = *(const short8*)&As[(wm * 64 + mi * 16 + r16) * 40 + quad * 8];
#pragma unroll
    for (int ni = 0; ni < 2; ni++)
      bfr[ni] = *(const short8*)&Bs[(wn * 32 + ni * 16 + r16) * 40 + quad * 8];
#pragma unroll
    for (int mi = 0; mi < 4; mi++)
#pragma unroll
      for (int ni = 0; ni < 2; ni++)
        acc[mi][ni] = __builtin_amdgcn_mfma_f32_16x16x32_bf16(afr[mi], bfr[ni], acc[mi][ni], 0, 0, 0);
    __syncthreads();
  }
#pragma unroll
  for (int mi = 0; mi < 4; mi++)
#pragma unroll
    for (int ni = 0; ni < 2; ni++)
#pragma unroll
      for (int r = 0; r < 4; r++)
        ab[(size_t)(m0 + wm * 64 + mi * 16 + quad * 4 + r) * (2 * DM)
           + n0 + wn * 32 + ni * 16 + r16] = acc[mi][ni][r];
}

// ---------------------------------------------------------------------------
// Depthwise causal conv (KER=4) + bias + silu on first half of ab -> x
// ---------------------------------------------------------------------------
__global__ __launch_bounds__(256)
void conv_silu_k(const float* __restrict__ ab, const float* __restrict__ cw,
                 const float* __restrict__ cb, float* __restrict__ x) {
  int idx = blockIdx.x * 256 + threadIdx.x;   // n*DM + d
  int d  = idx & (DM - 1);
  int n  = idx >> 10;
  int l  = n & (L_ - 1);
  int bb = n >> 10;
  float acc = cb[d];
#pragma unroll
  for (int k = 0; k < KER_; k++) {
    int ll = l - (KER_ - 1) + k;
    if (ll >= 0) acc += ab[(size_t)(bb * L_ + ll) * (2 * DM) + d] * cw[d * KER_ + k];
  }
  x[idx] = silu_f(acc);
}

// ---------------------------------------------------------------------------
// proj: pall[2048,96] += x[2048,1024] . [WB|WC|WD1][96,1024]^T
// split-K x8 (K=128/block, 4 iters), BM=64, BN=96, 256 thr = 4 waves,
// wave tile 16x96, reg-prefetch, atomicAdd epilogue (pall pre-zeroed).
// ---------------------------------------------------------------------------
__global__ __launch_bounds__(256)
void proj_k(const float* __restrict__ x, const float* __restrict__ WB,
            const float* __restrict__ WC, const float* __restrict__ WD1,
            float* __restrict__ pall) {
  __shared__ short As[64 * 40];
  __shared__ short Bs[96 * 40];
  const int tid  = threadIdx.x;
  const int lane = tid & 63;
  const int wave = tid >> 6;
  const int r16  = lane & 15;
  const int quad = lane >> 4;
  const int m0   = blockIdx.y * 64;
  const int kbeg = blockIdx.z * 128;
  float4v acc[6];
#pragma unroll
  for (int i = 0; i < 6; i++) acc[i] = (float4v){0.f, 0.f, 0.f, 0.f};
  float4 pf0[3], pf1[3];
  auto ldu = [&](int j, int k0) {
    int u = tid + j * 256;
    if (u >= 640) return;
    const float4* p;
    if (u < 256) { int row = u >> 2, q = u & 3;
      p = (const float4*)(x + (size_t)(m0 + row) * DM + k0 + q * 8);
    } else { int v = u - 256; int row = v >> 2, q = v & 3;
      const float* bp = (row < 16) ? (WB + (size_t)row * DM)
                      : (row < 32) ? (WC + (size_t)(row - 16) * DM)
                                   : (WD1 + (size_t)(row - 32) * DM);
      p = (const float4*)(bp + k0 + q * 8);
    }
    pf0[j] = p[0]; pf1[j] = p[1];
  };
  auto stu = [&](int j) {
    int u = tid + j * 256;
    if (u >= 640) return;
    short8 s = pack8(pf0[j], pf1[j]);
    if (u < 256) { int row = u >> 2, q = u & 3; *(short8*)&As[row * 40 + q * 8] = s; }
    else { int v = u - 256; int row = v >> 2, q = v & 3; *(short8*)&Bs[row * 40 + q * 8] = s; }
  };
  ldu(0, kbeg); ldu(1, kbeg); ldu(2, kbeg);
  for (int k0 = kbeg; k0 < kbeg + 128; k0 += 32) {
    stu(0); stu(1); stu(2);
    __syncthreads();
    if (k0 + 32 < kbeg + 128) { ldu(0, k0 + 32); ldu(1, k0 + 32); ldu(2, k0 + 32); }
    short8 afr = *(const short8*)&As[(wave * 16 + r16) * 40 + quad * 8];
#pragma unroll
    for (int ni = 0; ni < 6; ni++) {
      short8 bfr = *(const short8*)&Bs[(ni * 16 + r16) * 40 + quad * 8];
      acc[ni] = __builtin_amdgcn_mfma_f32_16x16x32_bf16(afr, bfr, acc[ni], 0, 0, 0);
    }
    __syncthreads();
  }
#pragma unroll
  for (int ni = 0; ni < 6; ni++) {
    int gn = ni * 16 + r16;
#pragma unroll
    for (int r = 0; r < 4; r++) {
      int gm = m0 + wave * 16 + quad * 4 + r;
      atomicAdd(&pall[(size_t)gm * 96 + gn], acc[ni][r]);
    }
  }
}

// ---------------------------------------------------------------------------
// delta: dlt[2048,1024] = softplus(t1[2048,64] . WD2[1024,64]^T + Dv)
// t1 lives in pall cols 32..95 (ld 96). BM=BN=64, K=64 (2 iters), 256 thr,
// waves 2x2, wave tile 32x32.
// ---------------------------------------------------------------------------
__global__ __launch_bounds__(256)
void delta_k(const float* __restrict__ t1, const float* __restrict__ WD2,
             const float* __restrict__ Dv, float* __restrict__ dlt) {
  __shared__ short As[64 * 40];
  __shared__ short Bs[64 * 40];
  const int tid  = threadIdx.x;
  const int lane = tid & 63;
  const int wave = tid >> 6;
  const int r16  = lane & 15;
  const int quad = lane >> 4;
  const int m0 = blockIdx.y * 64;
  const int n0 = blockIdx.x * 64;
  const int wm = wave & 1, wn = wave >> 1;
  float4v acc[2][2];
#pragma unroll
  for (int i = 0; i < 2; i++)
#pragma unroll
    for (int j = 0; j < 2; j++) acc[i][j] = (float4v){0.f, 0.f, 0.f, 0.f};
  float4 pf0[2], pf1[2];
  auto ldu = [&](int j, int k0) {
    int u = tid + j * 256;
    const float4* p;
    if (u < 256) { int row = u >> 2, q = u & 3;
      p = (const float4*)(t1 + (size_t)(m0 + row) * 96 + k0 + q * 8);
    } else { int v = u - 256; int row = v >> 2, q = v & 3;
      p = (const float4*)(WD2 + (size_t)(n0 + row) * DD + k0 + q * 8);
    }
    pf0[j] = p[0]; pf1[j] = p[1];
  };
  auto stu = [&](int j) {
    int u = tid + j * 256;
    short8 s = pack8(pf0[j], pf1[j]);
    if (u < 256) { int row = u >> 2, q = u & 3; *(short8*)&As[row * 40 + q * 8] = s; }
    else { int v = u - 256; int row = v >> 2, q = v & 3; *(short8*)&Bs[row * 40 + q * 8] = s; }
  };
  ldu(0, 0); ldu(1, 0);
  for (int k0 = 0; k0 < DD; k0 += 32) {
    stu(0); stu(1);
    __syncthreads();
    if (k0 + 32 < DD) { ldu(0, k0 + 32); ldu(1, k0 + 32); }
    short8 afr[2], bfr[2];
#pragma unroll
    for (int mi = 0; mi < 2; mi++)
      afr[mi] = *(const short8*)&As[(wm * 32 + mi * 16 + r16) * 40 + quad * 8];
#pragma unroll
    for (int ni = 0; ni < 2; ni++)
      bfr[ni] = *(const short8*)&Bs[(wn * 32 + ni * 16 + r16) * 40 + quad * 8];
#pragma unroll
    for (int mi = 0; mi < 2; mi++)
#pragma unroll
      for (int ni = 0; ni < 2; ni++)
        acc[mi][ni] = __builtin_amdgcn_mfma_f32_16x16x32_bf16(afr[mi], bfr[ni], acc[mi][ni], 0, 0, 0);
    __syncthreads();
  }
#pragma unroll
  for (int mi = 0; mi < 2; mi++)
#pragma unroll
    for (int ni = 0; ni < 2; ni++) {
      int gn = n0 + wn * 32 + ni * 16 + r16;
      float dvn = Dv[gn];
#pragma unroll
      for (int r = 0; r < 4; r++) {
        int gm = m0 + wm * 32 + mi * 16 + quad * 4 + r;
        float v = acc[mi][ni][r] + dvn;
        v = fmaxf(v, 0.f) + log1pf(expf(-fabsf(v)));   // stable softplus
        dlt[(size_t)gm * DM + gn] = v;
      }
    }
}

// ---------------------------------------------------------------------------
// Fused selective scan (R5/R6-verified math, x read directly).
// Block = (b, 8 d-lanes); chunk combine is LDS-local.
// ---------------------------------------------------------------------------
__global__ __launch_bounds__(256)
void scan_fused_k(const float* __restrict__ x, const float* __restrict__ dlt,
                  const float* __restrict__ pall, const float* __restrict__ A,
                  const float* __restrict__ Dv, const float* __restrict__ ab,
                  float* __restrict__ sout) {
  __shared__ float Pl[SC][DS][SDP];
  __shared__ float Hl[SC][DS][SDP];
  const int blk = blockIdx.x;
  const int b   = blk >> 7;
  const int d0  = (blk & 127) * SD;
  const int dd  = threadIdx.x & (SD - 1);
  const int c   = threadIdx.x >> 3;
  const int d   = d0 + dd;

  float e[DS];
#pragma unroll
  for (int s = 0; s < DS; s++) e[s] = expf(-A[d * DS + s]);
  const int nbase = b * L_ + c * SLC;

  float h[DS], p[DS];
#pragma unroll
  for (int s = 0; s < DS; s++) { h[s] = 0.f; p[s] = 1.f; }
  for (int i = 0; i < SLC; i++) {
    int n = nbase + i;
    float dl = dlt[(size_t)n * DM + d];
    float xv = x[(size_t)n * DM + d];
    float dx = dl * xv;
    const float4* bm4 = (const float4*)(pall + (size_t)n * 96);
    float4 b0 = bm4[0], b1 = bm4[1], b2 = bm4[2], b3 = bm4[3];
    float bmv[DS] = { b0.x,b0.y,b0.z,b0.w, b1.x,b1.y,b1.z,b1.w,
                      b2.x,b2.y,b2.z,b2.w, b3.x,b3.y,b3.z,b3.w };
#pragma unroll
    for (int s = 0; s < DS; s++) {
      float a_ = e[s] * dl;
      h[s] = a_ * h[s] + bmv[s] * dx;
      p[s] *= a_;
    }
  }
#pragma unroll
  for (int s = 0; s < DS; s++) { Pl[c][s][dd] = p[s]; Hl[c][s][dd] = h[s]; }
  __syncthreads();

  if (threadIdx.x < DS * SD) {
    int s2  = threadIdx.x >> 3;
    int dd2 = threadIdx.x & (SD - 1);
    float H = 0.f;
    for (int c2 = 0; c2 < SC; c2++) {
      float pp = Pl[c2][s2][dd2];
      float hh = Hl[c2][s2][dd2];
      Pl[c2][s2][dd2] = H;
      H = pp * H + hh;
    }
  }
  __syncthreads();

#pragma unroll
  for (int s = 0; s < DS; s++) h[s] = Pl[c][s][dd];
  float Dd = Dv[d];
  for (int i = 0; i < SLC; i++) {
    int n = nbase + i;
    float dl = dlt[(size_t)n * DM + d];
    float xv = x[(size_t)n * DM + d];
    float dx = dl * xv;
    const float4* bm4 = (const float4*)(pall + (size_t)n * 96);
    float4 b0 = bm4[0], b1 = bm4[1], b2 = bm4[2], b3 = bm4[3];
    float4 c0 = bm4[4], c1 = bm4[5], c2v = bm4[6], c3 = bm4[7];
    float bmv[DS] = { b0.x,b0.y,b0.z,b0.w, b1.x,b1.y,b1.z,b1.w,
                      b2.x,b2.y,b2.z,b2.w, b3.x,b3.y,b3.z,b3.w };
    float cmv[DS] = { c0.x,c0.y,c0.z,c0.w, c1.x,c1.y,c1.z,c1.w,
                      c2v.x,c2v.y,c2v.z,c2v.w, c3.x,c3.y,c3.z,c3.w };
    float y = 0.f;
#pragma unroll
    for (int s = 0; s < DS; s++) {
      h[s] = e[s] * dl * h[s] + bmv[s] * dx;
      y += h[s] * cmv[s];
    }
    y += Dd * xv;
    float g = ab[(size_t)n * (2 * DM) + DM + d];
    sout[(size_t)n * DM + d] = y * silu_f(g);
  }
}

// ---------------------------------------------------------------------------
// GEMM2: out[2048,512] = sout[2048,1024] . Wout[512,1024]^T
// 512 thr = 8 waves (2x4), BM=BN=64, wave tile 32x16, full K.
// ---------------------------------------------------------------------------
__global__ __launch_bounds__(512)
void gemm2_k(const float* __restrict__ sout, const float* __restrict__ Wout,
             float* __restrict__ out) {
  __shared__ short As[64 * 40];
  __shared__ short Bs[64 * 40];
  const int tid  = threadIdx.x;
  const int lane = tid & 63;
  const int wave = tid >> 6;
  const int r16  = lane & 15;
  const int quad = lane >> 4;
  const int m0 = blockIdx.y * 64;
  const int n0 = blockIdx.x * 64;
  const int wm = wave & 1, wn = wave >> 1;
  float4v acc[2];
  acc[0] = (float4v){0.f, 0.f, 0.f, 0.f};
  acc[1] = (float4v){0.f, 0.f, 0.f, 0.f};
  float4 pf0, pf1;
  auto ldu = [&](int k0) {
    const float4* p;
    if (tid < 256) { int row = tid >> 2, q = tid & 3;
      p = (const float4*)(sout + (size_t)(m0 + row) * DM + k0 + q * 8);
    } else { int v = tid - 256; int row = v >> 2, q = v & 3;
      p = (const float4*)(Wout + (size_t)(n0 + row) * DM + k0 + q * 8);
    }
    pf0 = p[0]; pf1 = p[1];
  };
  auto stu = [&]() {
    short8 s = pack8(pf0, pf1);
    if (tid < 256) { int row = tid >> 2, q = tid & 3; *(short8*)&As[row * 40 + q * 8] = s; }
    else { int v = tid - 256; int row = v >> 2, q = v & 3; *(short8*)&Bs[row * 40 + q * 8] = s; }
  };
  ldu(0);
  for (int k0 = 0; k0 < DM; k0 += 32) {
    stu();
    __syncthreads();
    if (k0 + 32 < DM) ldu(k0 + 32);
    short8 afr[2], bfr;
    afr[0] = *(const short8*)&As[(wm * 32 + r16) * 40 + quad * 8];
    afr[1] = *(const short8*)&As[(wm * 32 + 16 + r16) * 40 + quad * 8];
    bfr    = *(const short8*)&Bs[(wn * 16 + r16) * 40 + quad * 8];
    acc[0] = __builtin_amdgcn_mfma_f32_16x16x32_bf16(afr[0], bfr, acc[0], 0, 0, 0);
    acc[1] = __builtin_amdgcn_mfma_f32_16x16x32_bf16(afr[1], bfr, acc[1], 0, 0, 0);
    __syncthreads();
  }
#pragma unroll
  for (int mi = 0; mi < 2; mi++)
#pragma unroll
    for (int r = 0; r < 4; r++)
      out[(size_t)(m0 + wm * 32 + mi * 16 + quad * 4 + r) * DIN + n0 + wn * 16 + r16] = acc[mi][r];
}

// ---------------------------------------------------------------------------
extern "C" void kernel_launch(void* const* d_in, const int* in_sizes, int n_in,
                              void* d_out, int out_size, void* d_ws, size_t ws_size,
                              hipStream_t stream) {
  const float* seq  = (const float*)d_in[0];
  const float* Win  = (const float*)d_in[1];
  const float* Wout = (const float*)d_in[2];
  const float* WB   = (const float*)d_in[3];
  const float* WC   = (const float*)d_in[4];
  const float* WD1  = (const float*)d_in[5];
  const float* WD2  = (const float*)d_in[6];
  const float* cw   = (const float*)d_in[7];
  const float* cb   = (const float*)d_in[8];
  const float* A    = (const float*)d_in[9];
  const float* Dv   = (const float*)d_in[10];
  float* out = (float*)d_out;

  float* ws   = (float*)d_ws;
  float* ab   = ws;                   // 2048*2048 = 4194304
  float* x    = ab   + 4194304;       // 2048*1024 = 2097152
  float* dlt  = x    + 2097152;       // 2097152
  float* pall = dlt  + 2097152;       // 2048*96   = 196608  (Bm|Cm|t1)
  float* sout = pall + 196608;        // 2097152
  // total 42.7 MB (proven budget 47)
  float* t1   = pall + 32;            // t1 rows at col 32 (ld 96)

  hipMemsetAsync(pall, 0, (size_t)NROW * 96 * 4, stream);
  gemm1_k<<<dim3(16, 16), 512, 0, stream>>>(seq, Win, ab);
  conv_silu_k<<<NROW * DM / 256, 256, 0, stream>>>(ab, cw, cb, x);
  proj_k<<<dim3(1, 32, 8), 256, 0, stream>>>(x, WB, WC, WD1, pall);
  delta_k<<<dim3(16, 32), 256, 0, stream>>>(t1, WD2, Dv, dlt);
  scan_fused_k<<<B_ * (DM / SD), 256, 0, stream>>>(x, dlt, pall, A, Dv, ab, sout);
  gemm2_k<<<dim3(8, 32), 512, 0, stream>>>(sout, Wout, out);
}